// Round 8
// baseline (139.001 us; speedup 1.0000x reference)
//
#include <hip/hip_runtime.h>
#include <hip/hip_bf16.h>

// ConvDeepSet round 14: low-rank (Mehler, r=64) rebuilt defensively.
//  R13 postmortem: NaN from an unlocated bug in the new components (suspects:
//  hand-mapped B-frag workspace write, inline-asm cvt in new roles, unguarded
//  1/dens). This round removes every unverifiable assumption:
//  - G[k][c] computed in plain fp32 (no MFMA) and stored row-major; main
//    builds BOTH MFMA operand frags itself with the same slot convention
//    (correct under any hardware k-map, like R12's proven pairing).
//  - All new packing via software __float22bfloat162_rn (proven R0-R11).
//  - ff = 1/(max(dens,0)+1e-8): NaN-proof; upstream bugs become finite errors.
//  K = sum_k f_k(u) f_k(v), f_k(t) = e^{-t^2/2 ls^2-ish}: with w = x/ls,
//  f_0 = 2^{-(SSCALE*w)^2} = e^{-w^2/2}, f_k = f_{k-1} * w/sqrt(k).

#define N_CTX 2048
#define BATCH 16
#define M_TGT 4096
#define COUT  64
#define RDIM  128

#define WS_FB_OFF   0u                 // 8 MB fp32 fb[b][n][64k]
#define WS_G_OFF    0x800000u          // 1 MB fp32 G[b][64k][64c]
#define WS_GD_OFF   0x900000u          // 4 KB fp32 gd[b][64k]
#define WS_WT_OFF   0x901000u          // 16 KB bf16 Wt frag

#define SSCALE 0.8493222f   // sqrt(0.5 * log2(e))

typedef __attribute__((ext_vector_type(8)))  short        bf16x8;
typedef __attribute__((ext_vector_type(4)))  float        floatx4;
typedef __attribute__((ext_vector_type(4)))  unsigned int uint4v;

#if __has_builtin(__builtin_amdgcn_exp2f)
#define EXP2F __builtin_amdgcn_exp2f
#else
#define EXP2F exp2f
#endif

__constant__ float RSQ[64] = {
    0.0f,        1.0f,        0.70710678f, 0.57735027f, 0.5f,        0.44721360f,
    0.40824829f, 0.37796447f, 0.35355339f, 0.33333333f, 0.31622777f, 0.30151134f,
    0.28867513f, 0.27735010f, 0.26726124f, 0.25819889f, 0.25f,       0.24253563f,
    0.23570226f, 0.22941573f, 0.22360680f, 0.21821789f, 0.21320072f, 0.20851441f,
    0.20412415f, 0.2f,        0.19611614f, 0.19245009f, 0.18898224f, 0.18569534f,
    0.18257419f, 0.17960530f, 0.17677670f, 0.17407766f, 0.17149859f, 0.16903085f,
    0.16666667f, 0.16439899f, 0.16222142f, 0.16012815f, 0.15811388f, 0.15617376f,
    0.15430335f, 0.15249857f, 0.15075567f, 0.14907120f, 0.14744196f, 0.14586499f,
    0.14433757f, 0.14285714f, 0.14142136f, 0.14002801f, 0.13867505f, 0.13736056f,
    0.13608276f, 0.13483997f, 0.13363062f, 0.13245324f, 0.13130643f, 0.13018891f,
    0.12909944f, 0.12803688f, 0.12700013f, 0.12598816f };

// software RNE pack (proven R0-R11): low 16 = bf16(a), high 16 = bf16(b)
static __device__ __forceinline__ unsigned int packrn(float a, float b) {
    __hip_bfloat162 h = __float22bfloat162_rn(make_float2(a, b));
    return *reinterpret_cast<unsigned int*>(&h);
}
static __device__ __forceinline__ unsigned short f2bfs(float f) {
    __hip_bfloat16 h = __float2bfloat16(f);
    return *reinterpret_cast<unsigned short*>(&h);
}

// ---------------- wt: projection weights, bf16 frag layout ----------------
__global__ __launch_bounds__(256)
void convdeepset_wt(const float* __restrict__ W, unsigned char* __restrict__ ws)
{
    unsigned short* wt = (unsigned short*)(ws + WS_WT_OFF);
    for (int f = threadIdx.x; f < 8192; f += 256) {
        const int cp = f & 7, r = (f >> 3) & 127, ch = f >> 10;
        wt[ch * 1024 + r * 8 + cp] = f2bfs(W[r * 65 + 1 + ch * 8 + cp]);
    }
}

// ---------------- feat: context features fp32 [b][n][64] ----------------
__global__ __launch_bounds__(256)
void convdeepset_feat(const float* __restrict__ ci, const float* __restrict__ ls,
                      unsigned char* __restrict__ ws)
{
    float* fb = (float*)(ws + WS_FB_OFF);
    const int f = blockIdx.x * 256 + threadIdx.x;   // 0..32767
    const int n = f & 2047, bb = f >> 11;
    const float w  = ci[(size_t)n * BATCH + bb] / ls[0];
    const float sy = SSCALE * w;
    float v = EXP2F(-sy * sy);                      // f_0 = e^{-w^2/2}
    float4* o = (float4*)(fb + ((size_t)bb * 2048 + n) * 64);
    float4 c;
    c.x = v;
    v *= w * RSQ[1]; c.y = v;
    v *= w * RSQ[2]; c.z = v;
    v *= w * RSQ[3]; c.w = v;
    o[0] = c;
#pragma unroll
    for (int g = 1; g < 16; ++g) {
        v *= w * RSQ[4 * g];     c.x = v;
        v *= w * RSQ[4 * g + 1]; c.y = v;
        v *= w * RSQ[4 * g + 2]; c.z = v;
        v *= w * RSQ[4 * g + 3]; c.w = v;
        o[g] = c;
    }
}

// ------- g: G[b][k][c] = sum_n fb[b][n][k] * co[n][b][c], plain fp32 -------
__global__ __launch_bounds__(256)
void convdeepset_g(const float* __restrict__ co, unsigned char* __restrict__ ws)
{
    __shared__ float sred[16][256];
    __shared__ float sdens[16][4];
    const float* fb = (const float*)(ws + WS_FB_OFF);
    float* G  = (float*)(ws + WS_G_OFF);
    float* gd = (float*)(ws + WS_GD_OFF);
    const int b  = blockIdx.x & 15, kq = blockIdx.x >> 4;   // kq 0..15
    const int tid = threadIdx.x;
    const int c4 = tid & 15, q = tid >> 4;                  // q = n-chunk 0..15

    const float* cop = co + ((size_t)(q * 128) * BATCH + b) * COUT + c4 * 4;
    const float* fp  = fb + ((size_t)b * 2048 + q * 128) * 64 + kq * 4;
    float p[4][4];
#pragma unroll
    for (int ki = 0; ki < 4; ++ki)
#pragma unroll
        for (int ci = 0; ci < 4; ++ci) p[ki][ci] = 0.0f;
    float pd[4] = {0.0f, 0.0f, 0.0f, 0.0f};

    for (int n = 0; n < 128; ++n) {
        const float4 cv = *(const float4*)cop; cop += BATCH * COUT;
        const float4 fv = *(const float4*)fp;  fp  += 64;
        const float fvs[4] = {fv.x, fv.y, fv.z, fv.w};
        const float cvs[4] = {cv.x, cv.y, cv.z, cv.w};
#pragma unroll
        for (int ki = 0; ki < 4; ++ki)
#pragma unroll
            for (int ci = 0; ci < 4; ++ci)
                p[ki][ci] = __builtin_fmaf(fvs[ki], cvs[ci], p[ki][ci]);
        if (c4 == 0) {
#pragma unroll
            for (int ki = 0; ki < 4; ++ki) pd[ki] += fvs[ki];
        }
    }
#pragma unroll
    for (int ki = 0; ki < 4; ++ki)
#pragma unroll
        for (int ci = 0; ci < 4; ++ci)
            sred[q][ki * 64 + c4 * 4 + ci] = p[ki][ci];
    if (c4 == 0) {
#pragma unroll
        for (int ki = 0; ki < 4; ++ki) sdens[q][ki] = pd[ki];
    }
    __syncthreads();
    {
        const int ki = tid >> 6, c = tid & 63;
        float s = 0.0f;
#pragma unroll
        for (int q2 = 0; q2 < 16; ++q2) s += sred[q2][tid];
        G[((size_t)b * 64 + kq * 4 + ki) * 64 + c] = s;
    }
    if (tid < 4) {
        float s = 0.0f;
#pragma unroll
        for (int q2 = 0; q2 < 16; ++q2) s += sdens[q2][tid];
        gd[b * 64 + kq * 4 + tid] = s;
    }
}

// ---------------- main: target chain + compensated MFMA + projection ----------------
__global__ __launch_bounds__(256)
void convdeepset_main(const float* __restrict__ ti, const float* __restrict__ ls,
                      const float* __restrict__ W,  const float* __restrict__ bias,
                      const unsigned char* __restrict__ ws, float* __restrict__ out)
{
    __shared__ float gsm[4096];                  // 16 KB G[b] fp32
    __shared__ float gdl[64];
    __shared__ unsigned short vstage[4][1024];   //  8 KB, same-wave only

    const int tid  = threadIdx.x;
    const int lane = tid & 63;
    const int wv   = tid >> 6;
    const int g2   = lane >> 4;
    const int l15  = lane & 15;

    const int b  = blockIdx.x & 15;
    const int mt = blockIdx.x >> 4;              // 0..63
    const int m0 = mt * 64 + wv * 16;

    const float* Gg = (const float*)(ws + WS_G_OFF) + (size_t)b * 4096;
#pragma unroll
    for (int j = 0; j < 4; ++j)
        ((float4*)gsm)[tid + j * 256] = ((const float4*)Gg)[tid + j * 256];
    if (tid < 64) gdl[tid] = ((const float*)(ws + WS_GD_OFF))[b * 64 + tid];
    __syncthreads();

    const float w  = ti[(size_t)(m0 + l15) * BATCH + b] / ls[0];
    const float sy = SSCALE * w;
    float f = EXP2F(-sy * sy);
    float dens = f * gdl[0];
    float fs[16];
#pragma unroll
    for (int j = 0; j < 16; ++j) fs[j] = 0.0f;
    if (g2 == 0) fs[0] = f;
#pragma unroll
    for (int k = 1; k < 64; ++k) {
        f *= w * RSQ[k];
        dens += f * gdl[k];
        if (((k >> 3) & 3) == g2) fs[((k >> 5) << 3) | (k & 7)] = f;
    }

    // A-frags hi/lo (slot convention: element j of window w = feature w*32+g2*8+j)
    uint4v hw0, lw0, hw1, lw1;
#pragma unroll
    for (int p = 0; p < 4; ++p) {
        {
            const unsigned int h = packrn(fs[2 * p], fs[2 * p + 1]);
            const float e0 = __builtin_bit_cast(float, h << 16);
            const float e1 = __builtin_bit_cast(float, h & 0xffff0000u);
            hw0[p] = h;
            lw0[p] = packrn(fs[2 * p] - e0, fs[2 * p + 1] - e1);
        }
        {
            const unsigned int h = packrn(fs[8 + 2 * p], fs[8 + 2 * p + 1]);
            const float e0 = __builtin_bit_cast(float, h << 16);
            const float e1 = __builtin_bit_cast(float, h & 0xffff0000u);
            hw1[p] = h;
            lw1[p] = packrn(fs[8 + 2 * p] - e0, fs[8 + 2 * p + 1] - e1);
        }
    }
    const bf16x8 ah0 = __builtin_bit_cast(bf16x8, hw0);
    const bf16x8 al0 = __builtin_bit_cast(bf16x8, lw0);
    const bf16x8 ah1 = __builtin_bit_cast(bf16x8, hw1);
    const bf16x8 al1 = __builtin_bit_cast(bf16x8, lw1);

    // V[m][c] = sum_k f_k(v_m) G[k][c] via compensated MFMA (same slot conv both sides)
    floatx4 acc[4];
#pragma unroll
    for (int ct = 0; ct < 4; ++ct)
#pragma unroll
        for (int e = 0; e < 4; ++e) acc[ct][e] = 0.0f;
#pragma unroll
    for (int ct = 0; ct < 4; ++ct) {
#pragma unroll
        for (int wdw = 0; wdw < 2; ++wdw) {
            float gv[8];
#pragma unroll
            for (int j = 0; j < 8; ++j)
                gv[j] = gsm[(wdw * 32 + g2 * 8 + j) * 64 + ct * 16 + l15];
            uint4v gh, gl;
#pragma unroll
            for (int p = 0; p < 4; ++p) {
                const unsigned int h = packrn(gv[2 * p], gv[2 * p + 1]);
                const float e0 = __builtin_bit_cast(float, h << 16);
                const float e1 = __builtin_bit_cast(float, h & 0xffff0000u);
                gh[p] = h;
                gl[p] = packrn(gv[2 * p] - e0, gv[2 * p + 1] - e1);
            }
            const bf16x8 ghv = __builtin_bit_cast(bf16x8, gh);
            const bf16x8 glv = __builtin_bit_cast(bf16x8, gl);
            const bf16x8 ah = wdw ? ah1 : ah0;
            const bf16x8 al = wdw ? al1 : al0;
            acc[ct] = __builtin_amdgcn_mfma_f32_16x16x32_bf16(ah, ghv, acc[ct], 0, 0, 0);
            acc[ct] = __builtin_amdgcn_mfma_f32_16x16x32_bf16(al, ghv, acc[ct], 0, 0, 0);
            acc[ct] = __builtin_amdgcn_mfma_f32_16x16x32_bf16(ah, glv, acc[ct], 0, 0, 0);
        }
    }

    // ---- epilogue (R12-proven structure), guarded ff ----
    const unsigned short* wtg = (const unsigned short*)(ws + WS_WT_OFF);
    float dt[4], ffv[4];
#pragma unroll
    for (int reg = 0; reg < 4; ++reg) {
        const int m = (lane >> 4) * 4 + reg;            // C/D map row
        dt[reg]  = __shfl(dens, m, 64);                 // fp32 dens of row m
        ffv[reg] = 1.0f / (fmaxf(dt[reg], 0.0f) + 1e-8f);
    }
    unsigned short* vs = vstage[wv];
#pragma unroll
    for (int reg = 0; reg < 4; ++reg) {
        const int m = (lane >> 4) * 4 + reg;
#pragma unroll
        for (int q = 0; q < 4; ++q) {
            const int c = q * 16 + l15;
            vs[(c >> 3) * 128 + m * 8 + (c & 7)] = f2bfs(acc[q][reg]);
        }
    }
    floatx4 pacc[8];
#pragma unroll
    for (int rt = 0; rt < 8; ++rt)
#pragma unroll
        for (int e = 0; e < 4; ++e) pacc[rt][e] = 0.0f;
#pragma unroll
    for (int s2 = 0; s2 < 2; ++s2) {
        const int ch = s2 * 4 + g2;
        const bf16x8 avp = *(const bf16x8*)&vs[ch * 128 + l15 * 8];
#pragma unroll
        for (int rt = 0; rt < 8; ++rt) {
            const bf16x8 bvp = *(const bf16x8*)&wtg[ch * 1024 + (rt * 16 + l15) * 8];
            pacc[rt] = __builtin_amdgcn_mfma_f32_16x16x32_bf16(avp, bvp, pacc[rt], 0, 0, 0);
        }
    }
#pragma unroll
    for (int rt = 0; rt < 8; ++rt) {
        const int r = rt * 16 + l15;
        const float w0v = W[r * 65];
        const float bv  = bias[r];
#pragma unroll
        for (int reg = 0; reg < 4; ++reg) {
            const int m = (lane >> 4) * 4 + reg;
            out[((size_t)(m0 + m) * BATCH + b) * RDIM + r]
                = pacc[rt][reg] * ffv[reg] + dt[reg] * w0v + bv;
        }
    }
}

extern "C" void kernel_launch(void* const* d_in, const int* in_sizes, int n_in,
                              void* d_out, int out_size, void* d_ws, size_t ws_size,
                              hipStream_t stream) {
    const float* ci   = (const float*)d_in[0];  // context_in  (N,B,1)
    const float* co   = (const float*)d_in[1];  // context_out (N,B,64)
    const float* ti   = (const float*)d_in[2];  // target_in   (M,B,1)
    const float* ls   = (const float*)d_in[3];  // lengthscale (1,)
    const float* W    = (const float*)d_in[4];  // (128,65)
    const float* bias = (const float*)d_in[5];  // (128,)
    float* o = (float*)d_out;                   // (M,B,128)
    (void)in_sizes; (void)n_in; (void)out_size; (void)ws_size;

    unsigned char* ws = (unsigned char*)d_ws;
    convdeepset_wt<<<1, 256, 0, stream>>>(W, ws);
    convdeepset_feat<<<128, 256, 0, stream>>>(ci, ls, ws);
    convdeepset_g<<<256, 256, 0, stream>>>(co, ws);
    convdeepset_main<<<1024, 256, 0, stream>>>(ti, ls, W, bias, ws, o);
}

// Round 9
// 108.779 us; speedup vs baseline: 1.2778x; 1.2778x over previous
//
#include <hip/hip_runtime.h>
#include <hip/hip_bf16.h>

// ConvDeepSet round 15: low-rank pipeline with MFMA-based G build.
//  R14 postmortem: pipeline correct but convdeepset_g was latency-bound
//  (45-64us): 16x serial re-read of co (128MB L2 @ ~180GB/s) + dependent
//  scalar-FMA loop at 1 wave/SIMD. G[k][c] = sum_n f_k(u_n) co[n][c] is
//  exactly the R0-R12 main-loop GEMM shape -> rebuild g from proven parts:
//  - B-side: cow bf16 frag layout (prep byte-identical to R12's, verified).
//  - A-side: fp32 features from k-major fb[b][k][n] (R13 feat), packed
//    in-kernel with packrn, bf16x2-compensated (2 MFMA/ct).
//  - Grid 64 (16b x 4kt), 4 waves x 512 n, LDS partial-D reduce (R10 xred
//    pattern). gd fp32 exact via shfl + LDS reduce.
//  main kept VERBATIM from R14 (passed) to isolate the change.

#define N_CTX 2048
#define BATCH 16
#define M_TGT 4096
#define COUT  64
#define RDIM  128

#define WS_COW_OFF  0u                 // 4 MB bf16 cow frag [b][nblk][c][n&7]
#define WS_FB_OFF   0x400000u          // 8 MB fp32 fb[b][k][n]
#define WS_G_OFF    0xC00000u          // 256 KB fp32 G[b][64k][64c]
#define WS_GD_OFF   0xC40000u          // 4 KB fp32 gd[b][64k]
#define WS_WT_OFF   0xC41000u          // 16 KB bf16 Wt frag

#define SSCALE 0.8493222f   // sqrt(0.5 * log2(e))

typedef __attribute__((ext_vector_type(8)))  short        bf16x8;
typedef __attribute__((ext_vector_type(4)))  float        floatx4;
typedef __attribute__((ext_vector_type(4)))  unsigned int uint4v;

#if __has_builtin(__builtin_amdgcn_exp2f)
#define EXP2F __builtin_amdgcn_exp2f
#else
#define EXP2F exp2f
#endif

__constant__ float RSQ[64] = {
    0.0f,        1.0f,        0.70710678f, 0.57735027f, 0.5f,        0.44721360f,
    0.40824829f, 0.37796447f, 0.35355339f, 0.33333333f, 0.31622777f, 0.30151134f,
    0.28867513f, 0.27735010f, 0.26726124f, 0.25819889f, 0.25f,       0.24253563f,
    0.23570226f, 0.22941573f, 0.22360680f, 0.21821789f, 0.21320072f, 0.20851441f,
    0.20412415f, 0.2f,        0.19611614f, 0.19245009f, 0.18898224f, 0.18569534f,
    0.18257419f, 0.17960530f, 0.17677670f, 0.17407766f, 0.17149859f, 0.16903085f,
    0.16666667f, 0.16439899f, 0.16222142f, 0.16012815f, 0.15811388f, 0.15617376f,
    0.15430335f, 0.15249857f, 0.15075567f, 0.14907120f, 0.14744196f, 0.14586499f,
    0.14433757f, 0.14285714f, 0.14142136f, 0.14002801f, 0.13867505f, 0.13736056f,
    0.13608276f, 0.13483997f, 0.13363062f, 0.13245324f, 0.13130643f, 0.13018891f,
    0.12909944f, 0.12803688f, 0.12700013f, 0.12598816f };

// software RNE pack (proven R0-R11): low 16 = bf16(a), high 16 = bf16(b)
static __device__ __forceinline__ unsigned int packrn(float a, float b) {
    __hip_bfloat162 h = __float22bfloat162_rn(make_float2(a, b));
    return *reinterpret_cast<unsigned int*>(&h);
}
static __device__ __forceinline__ unsigned short f2bfs(float f) {
    __hip_bfloat16 h = __float2bfloat16(f);
    return *reinterpret_cast<unsigned short*>(&h);
}

// ---------------- prep: cow bf16 frag layout + Wt frag (R12-verbatim) ----------------
__global__ __launch_bounds__(256)
void convdeepset_prep(const float* __restrict__ co, const float* __restrict__ W,
                      unsigned char* __restrict__ ws)
{
    unsigned short* cow = (unsigned short*)(ws + WS_COW_OFF);
    unsigned short* wt  = (unsigned short*)(ws + WS_WT_OFF);
    const int blk = blockIdx.x, tid = threadIdx.x;

    if (blk < 1024) {
        const int g    = blk * 4 + (tid >> 6);
        const int bb   = g & 15;
        const int nblk = g >> 4;           // 0..255
        const int c    = tid & 63;
        const float* rp = co + ((size_t)nblk * 8 * BATCH + bb) * COUT + c;
        unsigned int u[4];
#pragma unroll
        for (int j = 0; j < 4; ++j) {
            const float f0 = rp[(size_t)(2 * j)     * BATCH * COUT];
            const float f1 = rp[(size_t)(2 * j + 1) * BATCH * COUT];
            u[j] = packrn(f0, f1);
        }
        *(uint4v*)&cow[(size_t)bb * 131072 + nblk * 512 + c * 8] = *(uint4v*)u;
    } else {
        for (int f = tid; f < 8192; f += 256) {
            const int cp = f & 7, r = (f >> 3) & 127, ch = f >> 10;
            wt[ch * 1024 + r * 8 + cp] = f2bfs(W[r * 65 + 1 + ch * 8 + cp]);
        }
    }
}

// ---------------- feat: context features fp32, k-major [b][k][n] ----------------
__global__ __launch_bounds__(256)
void convdeepset_feat(const float* __restrict__ ci, const float* __restrict__ ls,
                      unsigned char* __restrict__ ws)
{
    float* fb = (float*)(ws + WS_FB_OFF);
    const int f = blockIdx.x * 256 + threadIdx.x;   // 0..32767
    const int n = f & 2047, bb = f >> 11;
    const float w  = ci[(size_t)n * BATCH + bb] / ls[0];
    const float sy = SSCALE * w;
    float v = EXP2F(-sy * sy);                      // f_0 = e^{-w^2/2}
    float* o = fb + (size_t)bb * 64 * 2048 + n;
    o[0] = v;
#pragma unroll
    for (int k = 1; k < 64; ++k) {
        v *= w * RSQ[k];                            // f_k = f_{k-1} * w/sqrt(k)
        o[(size_t)k * 2048] = v;
    }
}

// ------- g: G[k][c] = sum_n f_k(u_n) co[n][c] via MFMA (R12-shaped loop) -------
__global__ __launch_bounds__(256)
void convdeepset_g(unsigned char* __restrict__ ws)
{
    __shared__ float sred[4][64][16];    // 16 KB partial D
    __shared__ float sdens[4][16];
    const unsigned short* cow = (const unsigned short*)(ws + WS_COW_OFF);
    const float* fb = (const float*)(ws + WS_FB_OFF);
    float* G  = (float*)(ws + WS_G_OFF);
    float* gd = (float*)(ws + WS_GD_OFF);

    const int b  = blockIdx.x >> 2, kt = blockIdx.x & 3;
    const int tid = threadIdx.x, lane = tid & 63, wv = tid >> 6;
    const int g2 = lane >> 4, l15 = lane & 15;

    // wave's n-range: ks = wv*16+s (s=0..15); n = ks*32 + g2*8 + j
    const float* ap = fb + ((size_t)b * 64 + kt * 16 + l15) * 2048
                    + wv * 512 + g2 * 8;
    const unsigned short* bp = cow + (size_t)b * 131072
                             + ((size_t)(wv * 16) * 4 + g2) * 512 + l15 * 8;

    floatx4 acc[4];
#pragma unroll
    for (int ct = 0; ct < 4; ++ct)
#pragma unroll
        for (int e = 0; e < 4; ++e) acc[ct][e] = 0.0f;
    float dpart = 0.0f;

#pragma unroll 4
    for (int s = 0; s < 16; ++s) {
        const floatx4 a0 = *(const floatx4*)(ap);
        const floatx4 a1 = *(const floatx4*)(ap + 4);
        ap += 32;
        const bf16x8 c0 = *(const bf16x8*)(bp);
        const bf16x8 c1 = *(const bf16x8*)(bp + 128);
        const bf16x8 c2 = *(const bf16x8*)(bp + 256);
        const bf16x8 c3 = *(const bf16x8*)(bp + 384);
        bp += 2048;
        dpart += a0.x + a0.y + a0.z + a0.w + a1.x + a1.y + a1.z + a1.w;
        const float fl[8] = {a0.x, a0.y, a0.z, a0.w, a1.x, a1.y, a1.z, a1.w};
        uint4v hw, lw;
#pragma unroll
        for (int p = 0; p < 4; ++p) {
            const unsigned int h = packrn(fl[2 * p], fl[2 * p + 1]);
            const float e0 = __builtin_bit_cast(float, h << 16);
            const float e1 = __builtin_bit_cast(float, h & 0xffff0000u);
            hw[p] = h;
            lw[p] = packrn(fl[2 * p] - e0, fl[2 * p + 1] - e1);
        }
        const bf16x8 ah = __builtin_bit_cast(bf16x8, hw);
        const bf16x8 al = __builtin_bit_cast(bf16x8, lw);
        acc[0] = __builtin_amdgcn_mfma_f32_16x16x32_bf16(ah, c0, acc[0], 0, 0, 0);
        acc[0] = __builtin_amdgcn_mfma_f32_16x16x32_bf16(al, c0, acc[0], 0, 0, 0);
        acc[1] = __builtin_amdgcn_mfma_f32_16x16x32_bf16(ah, c1, acc[1], 0, 0, 0);
        acc[1] = __builtin_amdgcn_mfma_f32_16x16x32_bf16(al, c1, acc[1], 0, 0, 0);
        acc[2] = __builtin_amdgcn_mfma_f32_16x16x32_bf16(ah, c2, acc[2], 0, 0, 0);
        acc[2] = __builtin_amdgcn_mfma_f32_16x16x32_bf16(al, c2, acc[2], 0, 0, 0);
        acc[3] = __builtin_amdgcn_mfma_f32_16x16x32_bf16(ah, c3, acc[3], 0, 0, 0);
        acc[3] = __builtin_amdgcn_mfma_f32_16x16x32_bf16(al, c3, acc[3], 0, 0, 0);
    }

    // dens: reduce over g2 (lane bits 4,5); k = kt*16 + l15
    dpart += __shfl_xor(dpart, 16);
    dpart += __shfl_xor(dpart, 32);
    if (lane < 16) sdens[wv][lane] = dpart;
#pragma unroll
    for (int ct = 0; ct < 4; ++ct)
#pragma unroll
        for (int reg = 0; reg < 4; ++reg)
            sred[wv][lane][ct * 4 + reg] = acc[ct][reg];
    __syncthreads();

    {   // cross-wave reduce + store: thread owns ct = tid>>6, lane's D slots
        const int ct = tid >> 6, ln = tid & 63;
        const int c  = ct * 16 + (ln & 15);
#pragma unroll
        for (int reg = 0; reg < 4; ++reg) {
            const float ssum = sred[0][ln][ct * 4 + reg] + sred[1][ln][ct * 4 + reg]
                             + sred[2][ln][ct * 4 + reg] + sred[3][ln][ct * 4 + reg];
            const int k = (ln >> 4) * 4 + reg;     // D map: row=(lane>>4)*4+reg
            G[((size_t)b * 64 + kt * 16 + k) * 64 + c] = ssum;
        }
    }
    if (tid < 16)
        gd[b * 64 + kt * 16 + tid]
            = sdens[0][tid] + sdens[1][tid] + sdens[2][tid] + sdens[3][tid];
}

// ---------------- main: R14-VERBATIM (passed) ----------------
__global__ __launch_bounds__(256)
void convdeepset_main(const float* __restrict__ ti, const float* __restrict__ ls,
                      const float* __restrict__ W,  const float* __restrict__ bias,
                      const unsigned char* __restrict__ ws, float* __restrict__ out)
{
    __shared__ float gsm[4096];                  // 16 KB G[b] fp32
    __shared__ float gdl[64];
    __shared__ unsigned short vstage[4][1024];   //  8 KB, same-wave only

    const int tid  = threadIdx.x;
    const int lane = tid & 63;
    const int wv   = tid >> 6;
    const int g2   = lane >> 4;
    const int l15  = lane & 15;

    const int b  = blockIdx.x & 15;
    const int mt = blockIdx.x >> 4;              // 0..63
    const int m0 = mt * 64 + wv * 16;

    const float* Gg = (const float*)(ws + WS_G_OFF) + (size_t)b * 4096;
#pragma unroll
    for (int j = 0; j < 4; ++j)
        ((float4*)gsm)[tid + j * 256] = ((const float4*)Gg)[tid + j * 256];
    if (tid < 64) gdl[tid] = ((const float*)(ws + WS_GD_OFF))[b * 64 + tid];
    __syncthreads();

    const float w  = ti[(size_t)(m0 + l15) * BATCH + b] / ls[0];
    const float sy = SSCALE * w;
    float f = EXP2F(-sy * sy);
    float dens = f * gdl[0];
    float fs[16];
#pragma unroll
    for (int j = 0; j < 16; ++j) fs[j] = 0.0f;
    if (g2 == 0) fs[0] = f;
#pragma unroll
    for (int k = 1; k < 64; ++k) {
        f *= w * RSQ[k];
        dens += f * gdl[k];
        if (((k >> 3) & 3) == g2) fs[((k >> 5) << 3) | (k & 7)] = f;
    }

    // A-frags hi/lo (slot convention: element j of window w = feature w*32+g2*8+j)
    uint4v hw0, lw0, hw1, lw1;
#pragma unroll
    for (int p = 0; p < 4; ++p) {
        {
            const unsigned int h = packrn(fs[2 * p], fs[2 * p + 1]);
            const float e0 = __builtin_bit_cast(float, h << 16);
            const float e1 = __builtin_bit_cast(float, h & 0xffff0000u);
            hw0[p] = h;
            lw0[p] = packrn(fs[2 * p] - e0, fs[2 * p + 1] - e1);
        }
        {
            const unsigned int h = packrn(fs[8 + 2 * p], fs[8 + 2 * p + 1]);
            const float e0 = __builtin_bit_cast(float, h << 16);
            const float e1 = __builtin_bit_cast(float, h & 0xffff0000u);
            hw1[p] = h;
            lw1[p] = packrn(fs[8 + 2 * p] - e0, fs[8 + 2 * p + 1] - e1);
        }
    }
    const bf16x8 ah0 = __builtin_bit_cast(bf16x8, hw0);
    const bf16x8 al0 = __builtin_bit_cast(bf16x8, lw0);
    const bf16x8 ah1 = __builtin_bit_cast(bf16x8, hw1);
    const bf16x8 al1 = __builtin_bit_cast(bf16x8, lw1);

    // V[m][c] = sum_k f_k(v_m) G[k][c] via compensated MFMA (same slot conv both sides)
    floatx4 acc[4];
#pragma unroll
    for (int ct = 0; ct < 4; ++ct)
#pragma unroll
        for (int e = 0; e < 4; ++e) acc[ct][e] = 0.0f;
#pragma unroll
    for (int ct = 0; ct < 4; ++ct) {
#pragma unroll
        for (int wdw = 0; wdw < 2; ++wdw) {
            float gv[8];
#pragma unroll
            for (int j = 0; j < 8; ++j)
                gv[j] = gsm[(wdw * 32 + g2 * 8 + j) * 64 + ct * 16 + l15];
            uint4v gh, gl;
#pragma unroll
            for (int p = 0; p < 4; ++p) {
                const unsigned int h = packrn(gv[2 * p], gv[2 * p + 1]);
                const float e0 = __builtin_bit_cast(float, h << 16);
                const float e1 = __builtin_bit_cast(float, h & 0xffff0000u);
                gh[p] = h;
                gl[p] = packrn(gv[2 * p] - e0, gv[2 * p + 1] - e1);
            }
            const bf16x8 ghv = __builtin_bit_cast(bf16x8, gh);
            const bf16x8 glv = __builtin_bit_cast(bf16x8, gl);
            const bf16x8 ah = wdw ? ah1 : ah0;
            const bf16x8 al = wdw ? al1 : al0;
            acc[ct] = __builtin_amdgcn_mfma_f32_16x16x32_bf16(ah, ghv, acc[ct], 0, 0, 0);
            acc[ct] = __builtin_amdgcn_mfma_f32_16x16x32_bf16(al, ghv, acc[ct], 0, 0, 0);
            acc[ct] = __builtin_amdgcn_mfma_f32_16x16x32_bf16(ah, glv, acc[ct], 0, 0, 0);
        }
    }

    // ---- epilogue (R12-proven structure), guarded ff ----
    const unsigned short* wtg = (const unsigned short*)(ws + WS_WT_OFF);
    float dt[4], ffv[4];
#pragma unroll
    for (int reg = 0; reg < 4; ++reg) {
        const int m = (lane >> 4) * 4 + reg;            // C/D map row
        dt[reg]  = __shfl(dens, m, 64);                 // fp32 dens of row m
        ffv[reg] = 1.0f / (fmaxf(dt[reg], 0.0f) + 1e-8f);
    }
    unsigned short* vs = vstage[wv];
#pragma unroll
    for (int reg = 0; reg < 4; ++reg) {
        const int m = (lane >> 4) * 4 + reg;
#pragma unroll
        for (int q = 0; q < 4; ++q) {
            const int c = q * 16 + l15;
            vs[(c >> 3) * 128 + m * 8 + (c & 7)] = f2bfs(acc[q][reg]);
        }
    }
    floatx4 pacc[8];
#pragma unroll
    for (int rt = 0; rt < 8; ++rt)
#pragma unroll
        for (int e = 0; e < 4; ++e) pacc[rt][e] = 0.0f;
#pragma unroll
    for (int s2 = 0; s2 < 2; ++s2) {
        const int ch = s2 * 4 + g2;
        const bf16x8 avp = *(const bf16x8*)&vs[ch * 128 + l15 * 8];
#pragma unroll
        for (int rt = 0; rt < 8; ++rt) {
            const bf16x8 bvp = *(const bf16x8*)&wtg[ch * 1024 + (rt * 16 + l15) * 8];
            pacc[rt] = __builtin_amdgcn_mfma_f32_16x16x32_bf16(avp, bvp, pacc[rt], 0, 0, 0);
        }
    }
#pragma unroll
    for (int rt = 0; rt < 8; ++rt) {
        const int r = rt * 16 + l15;
        const float w0v = W[r * 65];
        const float bv  = bias[r];
#pragma unroll
        for (int reg = 0; reg < 4; ++reg) {
            const int m = (lane >> 4) * 4 + reg;
            out[((size_t)(m0 + m) * BATCH + b) * RDIM + r]
                = pacc[rt][reg] * ffv[reg] + dt[reg] * w0v + bv;
        }
    }
}

extern "C" void kernel_launch(void* const* d_in, const int* in_sizes, int n_in,
                              void* d_out, int out_size, void* d_ws, size_t ws_size,
                              hipStream_t stream) {
    const float* ci   = (const float*)d_in[0];  // context_in  (N,B,1)
    const float* co   = (const float*)d_in[1];  // context_out (N,B,64)
    const float* ti   = (const float*)d_in[2];  // target_in   (M,B,1)
    const float* ls   = (const float*)d_in[3];  // lengthscale (1,)
    const float* W    = (const float*)d_in[4];  // (128,65)
    const float* bias = (const float*)d_in[5];  // (128,)
    float* o = (float*)d_out;                   // (M,B,128)
    (void)in_sizes; (void)n_in; (void)out_size; (void)ws_size;

    unsigned char* ws = (unsigned char*)d_ws;
    convdeepset_prep<<<1025, 256, 0, stream>>>(co, W, ws);
    convdeepset_feat<<<128, 256, 0, stream>>>(ci, ls, ws);
    convdeepset_g<<<64, 256, 0, stream>>>(ws);
    convdeepset_main<<<1024, 256, 0, stream>>>(ti, ls, W, bias, ws, o);
}

// Round 10
// 108.278 us; speedup vs baseline: 1.2837x; 1.0046x over previous
//
#include <hip/hip_runtime.h>
#include <hip/hip_bf16.h>

// ConvDeepSet round 16: consolidation of the low-rank pipeline (R15 passed,
//  108.8us total; all our kernels now below the harness's ~46us workspace
//  re-poison fills). Three cuts, no numerics change:
//  - wt+feat merged into prep (4 launches -> 3).
//  - main: 512 blocks x 2 m-tiles/wave; G-side bf16 hi/lo frags are
//    tile-invariant -> hoisted to registers once per block (halves LDS
//    reads + packs); dual feature chains interleave for 4-way ILP.
//  - g kernel and all numerics (compensated MFMA, guarded ffv) verbatim R15.

#define N_CTX 2048
#define BATCH 16
#define M_TGT 4096
#define COUT  64
#define RDIM  128

#define WS_COW_OFF  0u                 // 4 MB bf16 cow frag [b][nblk][c][n&7]
#define WS_FB_OFF   0x400000u          // 8 MB fp32 fb[b][k][n]
#define WS_G_OFF    0xC00000u          // 256 KB fp32 G[b][64k][64c]
#define WS_GD_OFF   0xC40000u          // 4 KB fp32 gd[b][64k]
#define WS_WT_OFF   0xC41000u          // 16 KB bf16 Wt frag

#define SSCALE 0.8493222f   // sqrt(0.5 * log2(e))

typedef __attribute__((ext_vector_type(8)))  short        bf16x8;
typedef __attribute__((ext_vector_type(4)))  float        floatx4;
typedef __attribute__((ext_vector_type(4)))  unsigned int uint4v;

#if __has_builtin(__builtin_amdgcn_exp2f)
#define EXP2F __builtin_amdgcn_exp2f
#else
#define EXP2F exp2f
#endif

__constant__ float RSQ[64] = {
    0.0f,        1.0f,        0.70710678f, 0.57735027f, 0.5f,        0.44721360f,
    0.40824829f, 0.37796447f, 0.35355339f, 0.33333333f, 0.31622777f, 0.30151134f,
    0.28867513f, 0.27735010f, 0.26726124f, 0.25819889f, 0.25f,       0.24253563f,
    0.23570226f, 0.22941573f, 0.22360680f, 0.21821789f, 0.21320072f, 0.20851441f,
    0.20412415f, 0.2f,        0.19611614f, 0.19245009f, 0.18898224f, 0.18569534f,
    0.18257419f, 0.17960530f, 0.17677670f, 0.17407766f, 0.17149859f, 0.16903085f,
    0.16666667f, 0.16439899f, 0.16222142f, 0.16012815f, 0.15811388f, 0.15617376f,
    0.15430335f, 0.15249857f, 0.15075567f, 0.14907120f, 0.14744196f, 0.14586499f,
    0.14433757f, 0.14285714f, 0.14142136f, 0.14002801f, 0.13867505f, 0.13736056f,
    0.13608276f, 0.13483997f, 0.13363062f, 0.13245324f, 0.13130643f, 0.13018891f,
    0.12909944f, 0.12803688f, 0.12700013f, 0.12598816f };

// software RNE pack (proven R0-R15): low 16 = bf16(a), high 16 = bf16(b)
static __device__ __forceinline__ unsigned int packrn(float a, float b) {
    __hip_bfloat162 h = __float22bfloat162_rn(make_float2(a, b));
    return *reinterpret_cast<unsigned int*>(&h);
}
static __device__ __forceinline__ unsigned short f2bfs(float f) {
    __hip_bfloat16 h = __float2bfloat16(f);
    return *reinterpret_cast<unsigned short*>(&h);
}

// -------- prep: cow frag + feat (fp32 k-major features) + Wt frag --------
__global__ __launch_bounds__(256)
void convdeepset_prep(const float* __restrict__ ci, const float* __restrict__ co,
                      const float* __restrict__ ls, const float* __restrict__ W,
                      unsigned char* __restrict__ ws)
{
    const int blk = blockIdx.x, tid = threadIdx.x;

    if (blk < 1024) {
        unsigned short* cow = (unsigned short*)(ws + WS_COW_OFF);
        const int g    = blk * 4 + (tid >> 6);
        const int bb   = g & 15;
        const int nblk = g >> 4;           // 0..255
        const int c    = tid & 63;
        const float* rp = co + ((size_t)nblk * 8 * BATCH + bb) * COUT + c;
        unsigned int u[4];
#pragma unroll
        for (int j = 0; j < 4; ++j) {
            const float f0 = rp[(size_t)(2 * j)     * BATCH * COUT];
            const float f1 = rp[(size_t)(2 * j + 1) * BATCH * COUT];
            u[j] = packrn(f0, f1);
        }
        *(uint4v*)&cow[(size_t)bb * 131072 + nblk * 512 + c * 8] = *(uint4v*)u;
    } else if (blk < 1152) {
        float* fbp = (float*)(ws + WS_FB_OFF);
        const int f = (blk - 1024) * 256 + tid;     // 0..32767
        const int n = f & 2047, bb = f >> 11;
        const float w  = ci[(size_t)n * BATCH + bb] / ls[0];
        const float sy = SSCALE * w;
        float v = EXP2F(-sy * sy);                  // f_0 = e^{-w^2/2}
        float* o = fbp + (size_t)bb * 64 * 2048 + n;
        o[0] = v;
#pragma unroll
        for (int k = 1; k < 64; ++k) {
            v *= w * RSQ[k];                        // f_k = f_{k-1} * w/sqrt(k)
            o[(size_t)k * 2048] = v;
        }
    } else {
        unsigned short* wt = (unsigned short*)(ws + WS_WT_OFF);
        for (int f = tid; f < 8192; f += 256) {
            const int cp = f & 7, r = (f >> 3) & 127, ch = f >> 10;
            wt[ch * 1024 + r * 8 + cp] = f2bfs(W[r * 65 + 1 + ch * 8 + cp]);
        }
    }
}

// ------- g: G[k][c] = sum_n f_k(u_n) co[n][c] via MFMA (R15-verbatim) -------
__global__ __launch_bounds__(256)
void convdeepset_g(unsigned char* __restrict__ ws)
{
    __shared__ float sred[4][64][16];    // 16 KB partial D
    __shared__ float sdens[4][16];
    const unsigned short* cow = (const unsigned short*)(ws + WS_COW_OFF);
    const float* fb = (const float*)(ws + WS_FB_OFF);
    float* G  = (float*)(ws + WS_G_OFF);
    float* gd = (float*)(ws + WS_GD_OFF);

    const int b  = blockIdx.x >> 2, kt = blockIdx.x & 3;
    const int tid = threadIdx.x, lane = tid & 63, wv = tid >> 6;
    const int g2 = lane >> 4, l15 = lane & 15;

    const float* ap = fb + ((size_t)b * 64 + kt * 16 + l15) * 2048
                    + wv * 512 + g2 * 8;
    const unsigned short* bp = cow + (size_t)b * 131072
                             + ((size_t)(wv * 16) * 4 + g2) * 512 + l15 * 8;

    floatx4 acc[4];
#pragma unroll
    for (int ct = 0; ct < 4; ++ct)
#pragma unroll
        for (int e = 0; e < 4; ++e) acc[ct][e] = 0.0f;
    float dpart = 0.0f;

#pragma unroll 4
    for (int s = 0; s < 16; ++s) {
        const floatx4 a0 = *(const floatx4*)(ap);
        const floatx4 a1 = *(const floatx4*)(ap + 4);
        ap += 32;
        const bf16x8 c0 = *(const bf16x8*)(bp);
        const bf16x8 c1 = *(const bf16x8*)(bp + 128);
        const bf16x8 c2 = *(const bf16x8*)(bp + 256);
        const bf16x8 c3 = *(const bf16x8*)(bp + 384);
        bp += 2048;
        dpart += a0.x + a0.y + a0.z + a0.w + a1.x + a1.y + a1.z + a1.w;
        const float fl[8] = {a0.x, a0.y, a0.z, a0.w, a1.x, a1.y, a1.z, a1.w};
        uint4v hw, lw;
#pragma unroll
        for (int p = 0; p < 4; ++p) {
            const unsigned int h = packrn(fl[2 * p], fl[2 * p + 1]);
            const float e0 = __builtin_bit_cast(float, h << 16);
            const float e1 = __builtin_bit_cast(float, h & 0xffff0000u);
            hw[p] = h;
            lw[p] = packrn(fl[2 * p] - e0, fl[2 * p + 1] - e1);
        }
        const bf16x8 ah = __builtin_bit_cast(bf16x8, hw);
        const bf16x8 al = __builtin_bit_cast(bf16x8, lw);
        acc[0] = __builtin_amdgcn_mfma_f32_16x16x32_bf16(ah, c0, acc[0], 0, 0, 0);
        acc[0] = __builtin_amdgcn_mfma_f32_16x16x32_bf16(al, c0, acc[0], 0, 0, 0);
        acc[1] = __builtin_amdgcn_mfma_f32_16x16x32_bf16(ah, c1, acc[1], 0, 0, 0);
        acc[1] = __builtin_amdgcn_mfma_f32_16x16x32_bf16(al, c1, acc[1], 0, 0, 0);
        acc[2] = __builtin_amdgcn_mfma_f32_16x16x32_bf16(ah, c2, acc[2], 0, 0, 0);
        acc[2] = __builtin_amdgcn_mfma_f32_16x16x32_bf16(al, c2, acc[2], 0, 0, 0);
        acc[3] = __builtin_amdgcn_mfma_f32_16x16x32_bf16(ah, c3, acc[3], 0, 0, 0);
        acc[3] = __builtin_amdgcn_mfma_f32_16x16x32_bf16(al, c3, acc[3], 0, 0, 0);
    }

    dpart += __shfl_xor(dpart, 16);
    dpart += __shfl_xor(dpart, 32);
    if (lane < 16) sdens[wv][lane] = dpart;
#pragma unroll
    for (int ct = 0; ct < 4; ++ct)
#pragma unroll
        for (int reg = 0; reg < 4; ++reg)
            sred[wv][lane][ct * 4 + reg] = acc[ct][reg];
    __syncthreads();

    {
        const int ct = tid >> 6, ln = tid & 63;
        const int c  = ct * 16 + (ln & 15);
#pragma unroll
        for (int reg = 0; reg < 4; ++reg) {
            const float ssum = sred[0][ln][ct * 4 + reg] + sred[1][ln][ct * 4 + reg]
                             + sred[2][ln][ct * 4 + reg] + sred[3][ln][ct * 4 + reg];
            const int k = (ln >> 4) * 4 + reg;     // D map: row=(lane>>4)*4+reg
            G[((size_t)b * 64 + kt * 16 + k) * 64 + c] = ssum;
        }
    }
    if (tid < 16)
        gd[b * 64 + kt * 16 + tid]
            = sdens[0][tid] + sdens[1][tid] + sdens[2][tid] + sdens[3][tid];
}

// -------- main: 2 m-tiles/wave, hoisted G-frags, dual chains --------
__global__ __launch_bounds__(256)
void convdeepset_main(const float* __restrict__ ti, const float* __restrict__ ls,
                      const float* __restrict__ W,  const float* __restrict__ bias,
                      const unsigned char* __restrict__ ws, float* __restrict__ out)
{
    __shared__ float gsm[4096];                  // 16 KB G[b] fp32
    __shared__ float gdl[64];
    __shared__ unsigned short vstage[4][1024];   //  8 KB, same-wave only

    const int tid  = threadIdx.x;
    const int lane = tid & 63;
    const int wv   = tid >> 6;
    const int g2   = lane >> 4;
    const int l15  = lane & 15;

    const int b  = blockIdx.x & 15;
    const int mt = blockIdx.x >> 4;              // 0..31
    const int m0 = mt * 128 + wv * 16;           // tile A rows; tile B = +64

    const float* Gg = (const float*)(ws + WS_G_OFF) + (size_t)b * 4096;
#pragma unroll
    for (int j = 0; j < 4; ++j)
        ((float4*)gsm)[tid + j * 256] = ((const float4*)Gg)[tid + j * 256];
    if (tid < 64) gdl[tid] = ((const float*)(ws + WS_GD_OFF))[b * 64 + tid];
    __syncthreads();

    // hoisted G-side frags (tile-invariant): hi/lo bf16, slot conv as R15
    bf16x8 ghv[4][2], glv[4][2];
#pragma unroll
    for (int ct = 0; ct < 4; ++ct)
#pragma unroll
        for (int wdw = 0; wdw < 2; ++wdw) {
            float gv[8];
#pragma unroll
            for (int j = 0; j < 8; ++j)
                gv[j] = gsm[(wdw * 32 + g2 * 8 + j) * 64 + ct * 16 + l15];
            uint4v gh, gl;
#pragma unroll
            for (int p = 0; p < 4; ++p) {
                const unsigned int h = packrn(gv[2 * p], gv[2 * p + 1]);
                const float e0 = __builtin_bit_cast(float, h << 16);
                const float e1 = __builtin_bit_cast(float, h & 0xffff0000u);
                gh[p] = h;
                gl[p] = packrn(gv[2 * p] - e0, gv[2 * p + 1] - e1);
            }
            ghv[ct][wdw] = __builtin_bit_cast(bf16x8, gh);
            glv[ct][wdw] = __builtin_bit_cast(bf16x8, gl);
        }

    // dual feature chains (4-way ILP)
    const float wa = ti[(size_t)(m0 + l15) * BATCH + b] / ls[0];
    const float wb = ti[(size_t)(m0 + 64 + l15) * BATCH + b] / ls[0];
    const float sa = SSCALE * wa, sb = SSCALE * wb;
    float fa  = EXP2F(-sa * sa);
    float fb_ = EXP2F(-sb * sb);
    float densa = fa * gdl[0], densb = fb_ * gdl[0];
    float fsa[16], fsb[16];
#pragma unroll
    for (int j = 0; j < 16; ++j) { fsa[j] = 0.0f; fsb[j] = 0.0f; }
    if (g2 == 0) { fsa[0] = fa; fsb[0] = fb_; }
#pragma unroll
    for (int k = 1; k < 64; ++k) {
        fa  *= wa * RSQ[k];
        fb_ *= wb * RSQ[k];
        densa += fa  * gdl[k];
        densb += fb_ * gdl[k];
        if (((k >> 3) & 3) == g2) {
            const int slot = ((k >> 5) << 3) | (k & 7);
            fsa[slot] = fa;
            fsb[slot] = fb_;
        }
    }

    const unsigned short* wtg = (const unsigned short*)(ws + WS_WT_OFF);

    auto do_tile = [&](const float (&fs)[16], float dens, int mbase) {
        // A-frags hi/lo
        uint4v hw0, lw0, hw1, lw1;
#pragma unroll
        for (int p = 0; p < 4; ++p) {
            {
                const unsigned int h = packrn(fs[2 * p], fs[2 * p + 1]);
                const float e0 = __builtin_bit_cast(float, h << 16);
                const float e1 = __builtin_bit_cast(float, h & 0xffff0000u);
                hw0[p] = h;
                lw0[p] = packrn(fs[2 * p] - e0, fs[2 * p + 1] - e1);
            }
            {
                const unsigned int h = packrn(fs[8 + 2 * p], fs[8 + 2 * p + 1]);
                const float e0 = __builtin_bit_cast(float, h << 16);
                const float e1 = __builtin_bit_cast(float, h & 0xffff0000u);
                hw1[p] = h;
                lw1[p] = packrn(fs[8 + 2 * p] - e0, fs[8 + 2 * p + 1] - e1);
            }
        }
        const bf16x8 ah0 = __builtin_bit_cast(bf16x8, hw0);
        const bf16x8 al0 = __builtin_bit_cast(bf16x8, lw0);
        const bf16x8 ah1 = __builtin_bit_cast(bf16x8, hw1);
        const bf16x8 al1 = __builtin_bit_cast(bf16x8, lw1);

        // V = sum_k f_k G[k][c], compensated (hoisted G frags)
        floatx4 acc[4];
#pragma unroll
        for (int ct = 0; ct < 4; ++ct)
#pragma unroll
            for (int e = 0; e < 4; ++e) acc[ct][e] = 0.0f;
#pragma unroll
        for (int ct = 0; ct < 4; ++ct) {
            acc[ct] = __builtin_amdgcn_mfma_f32_16x16x32_bf16(ah0, ghv[ct][0], acc[ct], 0, 0, 0);
            acc[ct] = __builtin_amdgcn_mfma_f32_16x16x32_bf16(al0, ghv[ct][0], acc[ct], 0, 0, 0);
            acc[ct] = __builtin_amdgcn_mfma_f32_16x16x32_bf16(ah0, glv[ct][0], acc[ct], 0, 0, 0);
            acc[ct] = __builtin_amdgcn_mfma_f32_16x16x32_bf16(ah1, ghv[ct][1], acc[ct], 0, 0, 0);
            acc[ct] = __builtin_amdgcn_mfma_f32_16x16x32_bf16(al1, ghv[ct][1], acc[ct], 0, 0, 0);
            acc[ct] = __builtin_amdgcn_mfma_f32_16x16x32_bf16(ah1, glv[ct][1], acc[ct], 0, 0, 0);
        }

        // epilogue (R12-proven structure), guarded ff
        float dt[4], ffv[4];
#pragma unroll
        for (int reg = 0; reg < 4; ++reg) {
            const int m = (lane >> 4) * 4 + reg;        // C/D map row
            dt[reg]  = __shfl(dens, m, 64);
            ffv[reg] = 1.0f / (fmaxf(dt[reg], 0.0f) + 1e-8f);
        }
        unsigned short* vs = vstage[wv];
#pragma unroll
        for (int reg = 0; reg < 4; ++reg) {
            const int m = (lane >> 4) * 4 + reg;
#pragma unroll
            for (int q = 0; q < 4; ++q) {
                const int c = q * 16 + l15;
                vs[(c >> 3) * 128 + m * 8 + (c & 7)] = f2bfs(acc[q][reg]);
            }
        }
        floatx4 pacc[8];
#pragma unroll
        for (int rt = 0; rt < 8; ++rt)
#pragma unroll
            for (int e = 0; e < 4; ++e) pacc[rt][e] = 0.0f;
#pragma unroll
        for (int s2 = 0; s2 < 2; ++s2) {
            const int ch = s2 * 4 + g2;
            const bf16x8 avp = *(const bf16x8*)&vs[ch * 128 + l15 * 8];
#pragma unroll
            for (int rt = 0; rt < 8; ++rt) {
                const bf16x8 bvp = *(const bf16x8*)&wtg[ch * 1024 + (rt * 16 + l15) * 8];
                pacc[rt] = __builtin_amdgcn_mfma_f32_16x16x32_bf16(avp, bvp, pacc[rt], 0, 0, 0);
            }
        }
#pragma unroll
        for (int rt = 0; rt < 8; ++rt) {
            const int r = rt * 16 + l15;
            const float w0v = W[r * 65];
            const float bv  = bias[r];
#pragma unroll
            for (int reg = 0; reg < 4; ++reg) {
                const int m = (lane >> 4) * 4 + reg;
                out[((size_t)(mbase + m) * BATCH + b) * RDIM + r]
                    = pacc[rt][reg] * ffv[reg] + dt[reg] * w0v + bv;
            }
        }
    };

    do_tile(fsa, densa, m0);
    do_tile(fsb, densb, m0 + 64);
}

extern "C" void kernel_launch(void* const* d_in, const int* in_sizes, int n_in,
                              void* d_out, int out_size, void* d_ws, size_t ws_size,
                              hipStream_t stream) {
    const float* ci   = (const float*)d_in[0];  // context_in  (N,B,1)
    const float* co   = (const float*)d_in[1];  // context_out (N,B,64)
    const float* ti   = (const float*)d_in[2];  // target_in   (M,B,1)
    const float* ls   = (const float*)d_in[3];  // lengthscale (1,)
    const float* W    = (const float*)d_in[4];  // (128,65)
    const float* bias = (const float*)d_in[5];  // (128,)
    float* o = (float*)d_out;                   // (M,B,128)
    (void)in_sizes; (void)n_in; (void)out_size; (void)ws_size;

    unsigned char* ws = (unsigned char*)d_ws;
    convdeepset_prep<<<1153, 256, 0, stream>>>(ci, co, ls, W, ws);
    convdeepset_g<<<64, 256, 0, stream>>>(ws);
    convdeepset_main<<<512, 256, 0, stream>>>(ti, ls, W, bias, ws, o);
}

// Round 12
// 106.771 us; speedup vs baseline: 1.3019x; 1.0141x over previous
//
#include <hip/hip_runtime.h>
#include <hip/hip_bf16.h>

// ConvDeepSet round 18: REVERT to round-16 (best passing, 108.3us).
//  R17 postmortem: single cooperative kernel failed correctness (absmax 3728)
//  - cross-XCD L2 non-coherence: phase-1 plain stores left dirty in writer
//  XCD's L2 were read stale by consumer blocks on other XCDs. The implicit
//  release/invalidate at kernel BOUNDARIES is what makes the 3-kernel
//  pipeline correct; __threadfence+grid.sync doesn't emit the needed
//  buffer_wbl2/buffer_inv for plain stores. Fixing = hand asm for ~2-6us;
//  per pre-commitment, not worth the correctness risk. This is R16 verbatim.
//
//  Pipeline (Mehler rank-64 factorization, exact to fp32 at this data range):
//   prep: cow bf16 frag + fb fp32 k-major features + Wt frag  (1153 blocks)
//   g:    G[k][c] = sum_n f_k(u_n) co[n][c] via compensated MFMA (64 blocks)
//   main: per-target 63-mul chain + fp32 dens + compensated MFMA + projection

#define N_CTX 2048
#define BATCH 16
#define M_TGT 4096
#define COUT  64
#define RDIM  128

#define WS_COW_OFF  0u                 // 4 MB bf16 cow frag [b][nblk][c][n&7]
#define WS_FB_OFF   0x400000u          // 8 MB fp32 fb[b][k][n]
#define WS_G_OFF    0xC00000u          // 256 KB fp32 G[b][64k][64c]
#define WS_GD_OFF   0xC40000u          // 4 KB fp32 gd[b][64k]
#define WS_WT_OFF   0xC41000u          // 16 KB bf16 Wt frag

#define SSCALE 0.8493222f   // sqrt(0.5 * log2(e))

typedef __attribute__((ext_vector_type(8)))  short        bf16x8;
typedef __attribute__((ext_vector_type(4)))  float        floatx4;
typedef __attribute__((ext_vector_type(4)))  unsigned int uint4v;

#if __has_builtin(__builtin_amdgcn_exp2f)
#define EXP2F __builtin_amdgcn_exp2f
#else
#define EXP2F exp2f
#endif

__constant__ float RSQ[64] = {
    0.0f,        1.0f,        0.70710678f, 0.57735027f, 0.5f,        0.44721360f,
    0.40824829f, 0.37796447f, 0.35355339f, 0.33333333f, 0.31622777f, 0.30151134f,
    0.28867513f, 0.27735010f, 0.26726124f, 0.25819889f, 0.25f,       0.24253563f,
    0.23570226f, 0.22941573f, 0.22360680f, 0.21821789f, 0.21320072f, 0.20851441f,
    0.20412415f, 0.2f,        0.19611614f, 0.19245009f, 0.18898224f, 0.18569534f,
    0.18257419f, 0.17960530f, 0.17677670f, 0.17407766f, 0.17149859f, 0.16903085f,
    0.16666667f, 0.16439899f, 0.16222142f, 0.16012815f, 0.15811388f, 0.15617376f,
    0.15430335f, 0.15249857f, 0.15075567f, 0.14907120f, 0.14744196f, 0.14586499f,
    0.14433757f, 0.14285714f, 0.14142136f, 0.14002801f, 0.13867505f, 0.13736056f,
    0.13608276f, 0.13483997f, 0.13363062f, 0.13245324f, 0.13130643f, 0.13018891f,
    0.12909944f, 0.12803688f, 0.12700013f, 0.12598816f };

// software RNE pack (proven R0-R16): low 16 = bf16(a), high 16 = bf16(b)
static __device__ __forceinline__ unsigned int packrn(float a, float b) {
    __hip_bfloat162 h = __float22bfloat162_rn(make_float2(a, b));
    return *reinterpret_cast<unsigned int*>(&h);
}
static __device__ __forceinline__ unsigned short f2bfs(float f) {
    __hip_bfloat16 h = __float2bfloat16(f);
    return *reinterpret_cast<unsigned short*>(&h);
}

// -------- prep: cow frag + feat (fp32 k-major features) + Wt frag --------
__global__ __launch_bounds__(256)
void convdeepset_prep(const float* __restrict__ ci, const float* __restrict__ co,
                      const float* __restrict__ ls, const float* __restrict__ W,
                      unsigned char* __restrict__ ws)
{
    const int blk = blockIdx.x, tid = threadIdx.x;

    if (blk < 1024) {
        unsigned short* cow = (unsigned short*)(ws + WS_COW_OFF);
        const int g    = blk * 4 + (tid >> 6);
        const int bb   = g & 15;
        const int nblk = g >> 4;           // 0..255
        const int c    = tid & 63;
        const float* rp = co + ((size_t)nblk * 8 * BATCH + bb) * COUT + c;
        unsigned int u[4];
#pragma unroll
        for (int j = 0; j < 4; ++j) {
            const float f0 = rp[(size_t)(2 * j)     * BATCH * COUT];
            const float f1 = rp[(size_t)(2 * j + 1) * BATCH * COUT];
            u[j] = packrn(f0, f1);
        }
        *(uint4v*)&cow[(size_t)bb * 131072 + nblk * 512 + c * 8] = *(uint4v*)u;
    } else if (blk < 1152) {
        float* fbp = (float*)(ws + WS_FB_OFF);
        const int f = (blk - 1024) * 256 + tid;     // 0..32767
        const int n = f & 2047, bb = f >> 11;
        const float w  = ci[(size_t)n * BATCH + bb] / ls[0];
        const float sy = SSCALE * w;
        float v = EXP2F(-sy * sy);                  // f_0 = e^{-w^2/2}
        float* o = fbp + (size_t)bb * 64 * 2048 + n;
        o[0] = v;
#pragma unroll
        for (int k = 1; k < 64; ++k) {
            v *= w * RSQ[k];                        // f_k = f_{k-1} * w/sqrt(k)
            o[(size_t)k * 2048] = v;
        }
    } else {
        unsigned short* wt = (unsigned short*)(ws + WS_WT_OFF);
        for (int f = tid; f < 8192; f += 256) {
            const int cp = f & 7, r = (f >> 3) & 127, ch = f >> 10;
            wt[ch * 1024 + r * 8 + cp] = f2bfs(W[r * 65 + 1 + ch * 8 + cp]);
        }
    }
}

// ------- g: G[k][c] = sum_n f_k(u_n) co[n][c] via MFMA (R15-verbatim) -------
__global__ __launch_bounds__(256)
void convdeepset_g(unsigned char* __restrict__ ws)
{
    __shared__ float sred[4][64][16];    // 16 KB partial D
    __shared__ float sdens[4][16];
    const unsigned short* cow = (const unsigned short*)(ws + WS_COW_OFF);
    const float* fb = (const float*)(ws + WS_FB_OFF);
    float* G  = (float*)(ws + WS_G_OFF);
    float* gd = (float*)(ws + WS_GD_OFF);

    const int b  = blockIdx.x >> 2, kt = blockIdx.x & 3;
    const int tid = threadIdx.x, lane = tid & 63, wv = tid >> 6;
    const int g2 = lane >> 4, l15 = lane & 15;

    const float* ap = fb + ((size_t)b * 64 + kt * 16 + l15) * 2048
                    + wv * 512 + g2 * 8;
    const unsigned short* bp = cow + (size_t)b * 131072
                             + ((size_t)(wv * 16) * 4 + g2) * 512 + l15 * 8;

    floatx4 acc[4];
#pragma unroll
    for (int ct = 0; ct < 4; ++ct)
#pragma unroll
        for (int e = 0; e < 4; ++e) acc[ct][e] = 0.0f;
    float dpart = 0.0f;

#pragma unroll 4
    for (int s = 0; s < 16; ++s) {
        const floatx4 a0 = *(const floatx4*)(ap);
        const floatx4 a1 = *(const floatx4*)(ap + 4);
        ap += 32;
        const bf16x8 c0 = *(const bf16x8*)(bp);
        const bf16x8 c1 = *(const bf16x8*)(bp + 128);
        const bf16x8 c2 = *(const bf16x8*)(bp + 256);
        const bf16x8 c3 = *(const bf16x8*)(bp + 384);
        bp += 2048;
        dpart += a0.x + a0.y + a0.z + a0.w + a1.x + a1.y + a1.z + a1.w;
        const float fl[8] = {a0.x, a0.y, a0.z, a0.w, a1.x, a1.y, a1.z, a1.w};
        uint4v hw, lw;
#pragma unroll
        for (int p = 0; p < 4; ++p) {
            const unsigned int h = packrn(fl[2 * p], fl[2 * p + 1]);
            const float e0 = __builtin_bit_cast(float, h << 16);
            const float e1 = __builtin_bit_cast(float, h & 0xffff0000u);
            hw[p] = h;
            lw[p] = packrn(fl[2 * p] - e0, fl[2 * p + 1] - e1);
        }
        const bf16x8 ah = __builtin_bit_cast(bf16x8, hw);
        const bf16x8 al = __builtin_bit_cast(bf16x8, lw);
        acc[0] = __builtin_amdgcn_mfma_f32_16x16x32_bf16(ah, c0, acc[0], 0, 0, 0);
        acc[0] = __builtin_amdgcn_mfma_f32_16x16x32_bf16(al, c0, acc[0], 0, 0, 0);
        acc[1] = __builtin_amdgcn_mfma_f32_16x16x32_bf16(ah, c1, acc[1], 0, 0, 0);
        acc[1] = __builtin_amdgcn_mfma_f32_16x16x32_bf16(al, c1, acc[1], 0, 0, 0);
        acc[2] = __builtin_amdgcn_mfma_f32_16x16x32_bf16(ah, c2, acc[2], 0, 0, 0);
        acc[2] = __builtin_amdgcn_mfma_f32_16x16x32_bf16(al, c2, acc[2], 0, 0, 0);
        acc[3] = __builtin_amdgcn_mfma_f32_16x16x32_bf16(ah, c3, acc[3], 0, 0, 0);
        acc[3] = __builtin_amdgcn_mfma_f32_16x16x32_bf16(al, c3, acc[3], 0, 0, 0);
    }

    dpart += __shfl_xor(dpart, 16);
    dpart += __shfl_xor(dpart, 32);
    if (lane < 16) sdens[wv][lane] = dpart;
#pragma unroll
    for (int ct = 0; ct < 4; ++ct)
#pragma unroll
        for (int reg = 0; reg < 4; ++reg)
            sred[wv][lane][ct * 4 + reg] = acc[ct][reg];
    __syncthreads();

    {
        const int ct = tid >> 6, ln = tid & 63;
        const int c  = ct * 16 + (ln & 15);
#pragma unroll
        for (int reg = 0; reg < 4; ++reg) {
            const float ssum = sred[0][ln][ct * 4 + reg] + sred[1][ln][ct * 4 + reg]
                             + sred[2][ln][ct * 4 + reg] + sred[3][ln][ct * 4 + reg];
            const int k = (ln >> 4) * 4 + reg;     // D map: row=(lane>>4)*4+reg
            G[((size_t)b * 64 + kt * 16 + k) * 64 + c] = ssum;
        }
    }
    if (tid < 16)
        gd[b * 64 + kt * 16 + tid]
            = sdens[0][tid] + sdens[1][tid] + sdens[2][tid] + sdens[3][tid];
}

// -------- main: 2 m-tiles/wave, hoisted G-frags, dual chains --------
__global__ __launch_bounds__(256)
void convdeepset_main(const float* __restrict__ ti, const float* __restrict__ ls,
                      const float* __restrict__ W,  const float* __restrict__ bias,
                      const unsigned char* __restrict__ ws, float* __restrict__ out)
{
    __shared__ float gsm[4096];                  // 16 KB G[b] fp32
    __shared__ float gdl[64];
    __shared__ unsigned short vstage[4][1024];   //  8 KB, same-wave only

    const int tid  = threadIdx.x;
    const int lane = tid & 63;
    const int wv   = tid >> 6;
    const int g2   = lane >> 4;
    const int l15  = lane & 15;

    const int b  = blockIdx.x & 15;
    const int mt = blockIdx.x >> 4;              // 0..31
    const int m0 = mt * 128 + wv * 16;           // tile A rows; tile B = +64

    const float* Gg = (const float*)(ws + WS_G_OFF) + (size_t)b * 4096;
#pragma unroll
    for (int j = 0; j < 4; ++j)
        ((float4*)gsm)[tid + j * 256] = ((const float4*)Gg)[tid + j * 256];
    if (tid < 64) gdl[tid] = ((const float*)(ws + WS_GD_OFF))[b * 64 + tid];
    __syncthreads();

    // hoisted G-side frags (tile-invariant): hi/lo bf16, slot conv as R15
    bf16x8 ghv[4][2], glv[4][2];
#pragma unroll
    for (int ct = 0; ct < 4; ++ct)
#pragma unroll
        for (int wdw = 0; wdw < 2; ++wdw) {
            float gv[8];
#pragma unroll
            for (int j = 0; j < 8; ++j)
                gv[j] = gsm[(wdw * 32 + g2 * 8 + j) * 64 + ct * 16 + l15];
            uint4v gh, gl;
#pragma unroll
            for (int p = 0; p < 4; ++p) {
                const unsigned int h = packrn(gv[2 * p], gv[2 * p + 1]);
                const float e0 = __builtin_bit_cast(float, h << 16);
                const float e1 = __builtin_bit_cast(float, h & 0xffff0000u);
                gh[p] = h;
                gl[p] = packrn(gv[2 * p] - e0, gv[2 * p + 1] - e1);
            }
            ghv[ct][wdw] = __builtin_bit_cast(bf16x8, gh);
            glv[ct][wdw] = __builtin_bit_cast(bf16x8, gl);
        }

    // dual feature chains (4-way ILP)
    const float wa = ti[(size_t)(m0 + l15) * BATCH + b] / ls[0];
    const float wb = ti[(size_t)(m0 + 64 + l15) * BATCH + b] / ls[0];
    const float sa = SSCALE * wa, sb = SSCALE * wb;
    float fa  = EXP2F(-sa * sa);
    float fb_ = EXP2F(-sb * sb);
    float densa = fa * gdl[0], densb = fb_ * gdl[0];
    float fsa[16], fsb[16];
#pragma unroll
    for (int j = 0; j < 16; ++j) { fsa[j] = 0.0f; fsb[j] = 0.0f; }
    if (g2 == 0) { fsa[0] = fa; fsb[0] = fb_; }
#pragma unroll
    for (int k = 1; k < 64; ++k) {
        fa  *= wa * RSQ[k];
        fb_ *= wb * RSQ[k];
        densa += fa  * gdl[k];
        densb += fb_ * gdl[k];
        if (((k >> 3) & 3) == g2) {
            const int slot = ((k >> 5) << 3) | (k & 7);
            fsa[slot] = fa;
            fsb[slot] = fb_;
        }
    }

    const unsigned short* wtg = (const unsigned short*)(ws + WS_WT_OFF);

    auto do_tile = [&](const float (&fs)[16], float dens, int mbase) {
        // A-frags hi/lo
        uint4v hw0, lw0, hw1, lw1;
#pragma unroll
        for (int p = 0; p < 4; ++p) {
            {
                const unsigned int h = packrn(fs[2 * p], fs[2 * p + 1]);
                const float e0 = __builtin_bit_cast(float, h << 16);
                const float e1 = __builtin_bit_cast(float, h & 0xffff0000u);
                hw0[p] = h;
                lw0[p] = packrn(fs[2 * p] - e0, fs[2 * p + 1] - e1);
            }
            {
                const unsigned int h = packrn(fs[8 + 2 * p], fs[8 + 2 * p + 1]);
                const float e0 = __builtin_bit_cast(float, h << 16);
                const float e1 = __builtin_bit_cast(float, h & 0xffff0000u);
                hw1[p] = h;
                lw1[p] = packrn(fs[8 + 2 * p] - e0, fs[8 + 2 * p + 1] - e1);
            }
        }
        const bf16x8 ah0 = __builtin_bit_cast(bf16x8, hw0);
        const bf16x8 al0 = __builtin_bit_cast(bf16x8, lw0);
        const bf16x8 ah1 = __builtin_bit_cast(bf16x8, hw1);
        const bf16x8 al1 = __builtin_bit_cast(bf16x8, lw1);

        // V = sum_k f_k G[k][c], compensated (hoisted G frags)
        floatx4 acc[4];
#pragma unroll
        for (int ct = 0; ct < 4; ++ct)
#pragma unroll
            for (int e = 0; e < 4; ++e) acc[ct][e] = 0.0f;
#pragma unroll
        for (int ct = 0; ct < 4; ++ct) {
            acc[ct] = __builtin_amdgcn_mfma_f32_16x16x32_bf16(ah0, ghv[ct][0], acc[ct], 0, 0, 0);
            acc[ct] = __builtin_amdgcn_mfma_f32_16x16x32_bf16(al0, ghv[ct][0], acc[ct], 0, 0, 0);
            acc[ct] = __builtin_amdgcn_mfma_f32_16x16x32_bf16(ah0, glv[ct][0], acc[ct], 0, 0, 0);
            acc[ct] = __builtin_amdgcn_mfma_f32_16x16x32_bf16(ah1, ghv[ct][1], acc[ct], 0, 0, 0);
            acc[ct] = __builtin_amdgcn_mfma_f32_16x16x32_bf16(al1, ghv[ct][1], acc[ct], 0, 0, 0);
            acc[ct] = __builtin_amdgcn_mfma_f32_16x16x32_bf16(ah1, glv[ct][1], acc[ct], 0, 0, 0);
        }

        // epilogue (R12-proven structure), guarded ff
        float dt[4], ffv[4];
#pragma unroll
        for (int reg = 0; reg < 4; ++reg) {
            const int m = (lane >> 4) * 4 + reg;        // C/D map row
            dt[reg]  = __shfl(dens, m, 64);
            ffv[reg] = 1.0f / (fmaxf(dt[reg], 0.0f) + 1e-8f);
        }
        unsigned short* vs = vstage[wv];
#pragma unroll
        for (int reg = 0; reg < 4; ++reg) {
            const int m = (lane >> 4) * 4 + reg;
#pragma unroll
            for (int q = 0; q < 4; ++q) {
                const int c = q * 16 + l15;
                vs[(c >> 3) * 128 + m * 8 + (c & 7)] = f2bfs(acc[q][reg]);
            }
        }
        floatx4 pacc[8];
#pragma unroll
        for (int rt = 0; rt < 8; ++rt)
#pragma unroll
            for (int e = 0; e < 4; ++e) pacc[rt][e] = 0.0f;
#pragma unroll
        for (int s2 = 0; s2 < 2; ++s2) {
            const int ch = s2 * 4 + g2;
            const bf16x8 avp = *(const bf16x8*)&vs[ch * 128 + l15 * 8];
#pragma unroll
            for (int rt = 0; rt < 8; ++rt) {
                const bf16x8 bvp = *(const bf16x8*)&wtg[ch * 1024 + (rt * 16 + l15) * 8];
                pacc[rt] = __builtin_amdgcn_mfma_f32_16x16x32_bf16(avp, bvp, pacc[rt], 0, 0, 0);
            }
        }
#pragma unroll
        for (int rt = 0; rt < 8; ++rt) {
            const int r = rt * 16 + l15;
            const float w0v = W[r * 65];
            const float bv  = bias[r];
#pragma unroll
            for (int reg = 0; reg < 4; ++reg) {
                const int m = (lane >> 4) * 4 + reg;
                out[((size_t)(mbase + m) * BATCH + b) * RDIM + r]
                    = pacc[rt][reg] * ffv[reg] + dt[reg] * w0v + bv;
            }
        }
    };

    do_tile(fsa, densa, m0);
    do_tile(fsb, densb, m0 + 64);
}

extern "C" void kernel_launch(void* const* d_in, const int* in_sizes, int n_in,
                              void* d_out, int out_size, void* d_ws, size_t ws_size,
                              hipStream_t stream) {
    const float* ci   = (const float*)d_in[0];  // context_in  (N,B,1)
    const float* co   = (const float*)d_in[1];  // context_out (N,B,64)
    const float* ti   = (const float*)d_in[2];  // target_in   (M,B,1)
    const float* ls   = (const float*)d_in[3];  // lengthscale (1,)
    const float* W    = (const float*)d_in[4];  // (128,65)
    const float* bias = (const float*)d_in[5];  // (128,)
    float* o = (float*)d_out;                   // (M,B,128)
    (void)in_sizes; (void)n_in; (void)out_size; (void)ws_size;

    unsigned char* ws = (unsigned char*)d_ws;
    convdeepset_prep<<<1153, 256, 0, stream>>>(ci, co, ls, W, ws);
    convdeepset_g<<<64, 256, 0, stream>>>(ws);
    convdeepset_main<<<512, 256, 0, stream>>>(ti, ls, W, bias, ws, o);
}